// Round 14
// baseline (242.615 us; speedup 1.0000x reference)
//
#include <hip/hip_runtime.h>

#define NB 128
#define NS 8192
#define NC 128                // chunks per sequence (64-step chunks)
#define NCP 8                 // combined matrices per sequence (one per block)
#define NL (NS / NC)          // 64 steps per chunk
#define M4 (NL / 4)           // 16 float4 groups

#define LOG2E 1.4426950408889634f
#define HLOG2PI 0.918938533204672742f
#define LN2 0.69314718055994531f

// LDS matrix layout (r6/8/9/11/12/13-proven)
#define ROWS 20          // padded leading dim
#define UNIT 640         // dual unit: R[16x20] + T[16x20]
#define SLOT 320

__device__ __forceinline__ float fexp2(float x) { return __builtin_amdgcn_exp2f(x); }
__device__ __forceinline__ float flog2(float x) { return __builtin_amdgcn_logf(x); }

__device__ __forceinline__ float gsum16(float v) {
    v += __shfl_xor(v, 1, 16);
    v += __shfl_xor(v, 2, 16);
    v += __shfl_xor(v, 4, 16);
    v += __shfl_xor(v, 8, 16);
    return v;
}
__device__ __forceinline__ float gmax16(float v) {
    v = fmaxf(v, __shfl_xor(v, 1, 16));
    v = fmaxf(v, __shfl_xor(v, 2, 16));
    v = fmaxf(v, __shfl_xor(v, 4, 16));
    v = fmaxf(v, __shfl_xor(v, 8, 16));
    return v;
}

template <int K>
__device__ __forceinline__ int rotk(int x) {
    return __builtin_amdgcn_mov_dpp(x, 0x120 + K, 0xF, 0xF, true);
}

// One HMM step in rotated-W layout (r8/9/11/12/13-proven scalar form).
__device__ __forceinline__ float step2(float (&W)[16], float T, float xx,
                                       float A2, float B2, float C2) {
    const float amb = 0.9f - 0.1f / 15.0f;
    const float bco = 0.1f / 15.0f;
    float myl = fexp2(fmaf(xx, fmaf(xx, A2, B2), C2));   // ONE exp per lane
    int mi = __float_as_int(myl);
    float bT = bco * T;
    W[0]  = fmaf(amb, W[0],  bT) * myl;
    W[1]  = fmaf(amb, W[1],  bT) * __int_as_float(rotk<1>(mi));
    W[2]  = fmaf(amb, W[2],  bT) * __int_as_float(rotk<2>(mi));
    W[3]  = fmaf(amb, W[3],  bT) * __int_as_float(rotk<3>(mi));
    W[4]  = fmaf(amb, W[4],  bT) * __int_as_float(rotk<4>(mi));
    W[5]  = fmaf(amb, W[5],  bT) * __int_as_float(rotk<5>(mi));
    W[6]  = fmaf(amb, W[6],  bT) * __int_as_float(rotk<6>(mi));
    W[7]  = fmaf(amb, W[7],  bT) * __int_as_float(rotk<7>(mi));
    W[8]  = fmaf(amb, W[8],  bT) * __int_as_float(rotk<8>(mi));
    W[9]  = fmaf(amb, W[9],  bT) * __int_as_float(rotk<9>(mi));
    W[10] = fmaf(amb, W[10], bT) * __int_as_float(rotk<10>(mi));
    W[11] = fmaf(amb, W[11], bT) * __int_as_float(rotk<11>(mi));
    W[12] = fmaf(amb, W[12], bT) * __int_as_float(rotk<12>(mi));
    W[13] = fmaf(amb, W[13], bT) * __int_as_float(rotk<13>(mi));
    W[14] = fmaf(amb, W[14], bT) * __int_as_float(rotk<14>(mi));
    W[15] = fmaf(amb, W[15], bT) * __int_as_float(rotk<15>(mi));
    float s0 = (W[0] + W[1]) + (W[2] + W[3]);
    float s1 = (W[4] + W[5]) + (W[6] + W[7]);
    float s2 = (W[8] + W[9]) + (W[10] + W[11]);
    float s3 = (W[12] + W[13]) + (W[14] + W[15]);
    return (s0 + s1) + (s2 + s3);
}

// Renormalized product of two LDS dual units (r12/13-proven).
__device__ __forceinline__ void combineUnits(float* lds, int ua, int ub, int ud, int lane) {
    const float* MbR = lds + ub * UNIT;
    const float* MaT = lds + ua * UNIT + SLOT;
    float mxa = lds[ua * UNIT + 16];
    float mxb = lds[ub * UNIT + 16];
    int a = lane >> 3, cc = lane & 7;
    float b0[16], b1[16], a0[16], a1[16];
    const float4* pb0 = (const float4*)(MbR + (2 * a) * ROWS);
    const float4* pb1 = (const float4*)(MbR + (2 * a + 1) * ROWS);
    const float4* pa0 = (const float4*)(MaT + (2 * cc) * ROWS);
    const float4* pa1 = (const float4*)(MaT + (2 * cc + 1) * ROWS);
#pragma unroll
    for (int q = 0; q < 4; ++q) {
        *(float4*)&b0[4 * q] = pb0[q];
        *(float4*)&b1[4 * q] = pb1[q];
        *(float4*)&a0[4 * q] = pa0[q];
        *(float4*)&a1[4 * q] = pa1[q];
    }
    float c00 = 0.f, c01 = 0.f, c10 = 0.f, c11 = 0.f;
#pragma unroll
    for (int k = 0; k < 16; ++k) {
        c00 = fmaf(b0[k], a0[k], c00);
        c01 = fmaf(b0[k], a1[k], c01);
        c10 = fmaf(b1[k], a0[k], c10);
        c11 = fmaf(b1[k], a1[k], c11);
    }
    float cs0 = c00 + c10;
    float cs1 = c01 + c11;
    cs0 += __shfl_xor(cs0, 8);  cs1 += __shfl_xor(cs1, 8);
    cs0 += __shfl_xor(cs0, 16); cs1 += __shfl_xor(cs1, 16);
    cs0 += __shfl_xor(cs0, 32); cs1 += __shfl_xor(cs1, 32);
    float mxc = fmaxf(cs0, cs1);
    mxc = fmaxf(mxc, __shfl_xor(mxc, 1));
    mxc = fmaxf(mxc, __shfl_xor(mxc, 2));
    mxc = fmaxf(mxc, __shfl_xor(mxc, 4));
    float is = 1.0f / mxc;
    c00 *= is; c01 *= is; c10 *= is; c11 *= is;
    float* dR = lds + ud * UNIT;
    float* dT = lds + ud * UNIT + SLOT;
    *(float2*)(dR + (2 * a) * ROWS + 2 * cc)     = make_float2(c00, c01);
    *(float2*)(dR + (2 * a + 1) * ROWS + 2 * cc) = make_float2(c10, c11);
    *(float2*)(dT + (2 * cc) * ROWS + 2 * a)     = make_float2(c00, c10);
    *(float2*)(dT + (2 * cc + 1) * ROWS + 2 * a) = make_float2(c01, c11);
    if (lane == 0) lds[ud * UNIT + 16] = mxa + mxb + flog2(mxc);
}

// P = Mb * Ma, one product per wave, unnormalized (r13 epilogue tree; 3 levels safe).
__device__ __forceinline__ void mat16_mul(float* dR, float* dT,
                                          const float* MbR, const float* MaT,
                                          int lane) {
    int a = lane >> 3;
    int cc = lane & 7;
    float b0[16], b1[16], a0[16], a1[16];
    const float4* pb0 = (const float4*)(MbR + (2 * a) * ROWS);
    const float4* pb1 = (const float4*)(MbR + (2 * a + 1) * ROWS);
    const float4* pa0 = (const float4*)(MaT + (2 * cc) * ROWS);
    const float4* pa1 = (const float4*)(MaT + (2 * cc + 1) * ROWS);
#pragma unroll
    for (int q = 0; q < 4; ++q) {
        *(float4*)&b0[4 * q] = pb0[q];
        *(float4*)&b1[4 * q] = pb1[q];
        *(float4*)&a0[4 * q] = pa0[q];
        *(float4*)&a1[4 * q] = pa1[q];
    }
    float c00 = 0.f, c01 = 0.f, c10 = 0.f, c11 = 0.f;
#pragma unroll
    for (int k = 0; k < 16; ++k) {
        c00 = fmaf(b0[k], a0[k], c00);
        c01 = fmaf(b0[k], a1[k], c01);
        c10 = fmaf(b1[k], a0[k], c10);
        c11 = fmaf(b1[k], a1[k], c11);
    }
    *(float2*)(dR + (2 * a) * ROWS + 2 * cc)     = make_float2(c00, c01);
    *(float2*)(dR + (2 * a + 1) * ROWS + 2 * cc) = make_float2(c10, c11);
    if (dT) {
        *(float2*)(dT + (2 * cc) * ROWS + 2 * a)     = make_float2(c00, c10);
        *(float2*)(dT + (2 * cc + 1) * ROWS + 2 * a) = make_float2(c01, c11);
    }
}

// Single fused kernel. Per block: r13 phase1 verbatim (64-step chunk scan,
// in-LDS renormalized 16->1 tree, emit 1 mat). Then the threadfence-reduction
// pattern: 8 blocks per b; the LAST to arrive (per-b atomic counter vs a
// never-written reference word — correct under any uniform ws poison) inlines
// r13's phase23 for that b and writes resOut[b]; the globally-last of all 1024
// blocks sums resOut into out[0]. No spins, no pre-zeroing, one dispatch.
// LDS stays 40,960 B (flag/partials overlaid in unit 15) -> 4 blocks/CU.
__global__ __launch_bounds__(256, 4) void hmm_fused(const float* __restrict__ obvs,
                                                    const float* __restrict__ mu,
                                                    const float* __restrict__ log_sigma,
                                                    const float* __restrict__ prior_logits,
                                                    float* __restrict__ wsW,
                                                    float* __restrict__ wsM,
                                                    float* __restrict__ resOut,
                                                    unsigned* __restrict__ cntB,
                                                    unsigned* __restrict__ cntG,
                                                    const unsigned* __restrict__ refW,
                                                    float* __restrict__ out) {
    __shared__ float lds[16 * UNIT];       // 16 dual units, 40,960 B exactly
    int tid = blockIdx.x * 256 + threadIdx.x;
    int r = threadIdx.x & 15;
    int u = threadIdx.x >> 4;              // local chunk 0..15
    int g = tid >> 4;                      // g = b*NC + c
    int b = g >> 7;
    int c = g & (NC - 1);

    float ls = log_sigma[r];
    float mk = mu[r];
    float iv = fexp2(-2.0f * LOG2E * ls);
    float A2 = -0.5f * LOG2E * iv;
    float B2 = LOG2E * mk * iv;
    float C2 = LOG2E * (-0.5f * mk * mk * iv - ls - HLOG2PI);

    float W[16];
#pragma unroll
    for (int k = 0; k < 16; ++k) W[k] = (k == 0) ? 1.0f : 0.0f;  // identity, rotated layout
    int ilog = 0;
    float T = 1.0f;

    const float4* ob4 = (const float4*)(obvs + (long)b * NS) + c * M4;
    float4 xv = ob4[0];
    float4 xn = ob4[1];
    // peeled m=0 group: chunk 0 skips t=0 (handled as init vector in the epilogue)
    if (c) T = step2(W, T, xv.x, A2, B2, C2);
    T = step2(W, T, xv.y, A2, B2, C2);
    T = step2(W, T, xv.z, A2, B2, C2);
    T = step2(W, T, xv.w, A2, B2, C2);
    {
        int te = (__float_as_int(T) >> 23) & 255;
        int ok = (te != 0);
        float s = ok ? __int_as_float((254 - te) << 23) : 1.0f;
        ilog += ok ? (te - 127) : 0;
#pragma unroll
        for (int k = 0; k < 16; ++k) W[k] *= s;
        T *= s;
    }
    xv = xn;
    for (int m = 1; m < M4; ++m) {
        xn = ob4[(m + 1) < M4 ? (m + 1) : m];
        T = step2(W, T, xv.x, A2, B2, C2);
        T = step2(W, T, xv.y, A2, B2, C2);
        T = step2(W, T, xv.z, A2, B2, C2);
        T = step2(W, T, xv.w, A2, B2, C2);
        // guarded branchless exponent renorm (r8/9/11/12/13-proven)
        int te = (__float_as_int(T) >> 23) & 255;
        int ok = (te != 0);
        float s = ok ? __int_as_float((254 - te) << 23) : 1.0f;
        ilog += ok ? (te - 127) : 0;
#pragma unroll
        for (int k = 0; k < 16; ++k) W[k] *= s;
        T *= s;
        xv = xn;
    }

    int sid[16];
    sid[0] = r;
    sid[1]  = rotk<1>(r);   sid[2]  = rotk<2>(r);   sid[3]  = rotk<3>(r);
    sid[4]  = rotk<4>(r);   sid[5]  = rotk<5>(r);   sid[6]  = rotk<6>(r);
    sid[7]  = rotk<7>(r);   sid[8]  = rotk<8>(r);   sid[9]  = rotk<9>(r);
    sid[10] = rotk<10>(r);  sid[11] = rotk<11>(r);  sid[12] = rotk<12>(r);
    sid[13] = rotk<13>(r);  sid[14] = rotk<14>(r);  sid[15] = rotk<15>(r);

    float lg = (float)ilog + flog2(T);
    float mx = gmax16(lg);
    float sc = fexp2((float)ilog - mx);

    // normalized chunk matrix into LDS dual layout; mx in the j=0 pad hole
    {
        float* Ru = lds + u * UNIT;
        float* Tu = lds + u * UNIT + SLOT;
#pragma unroll
        for (int k = 0; k < 16; ++k) {
            float w = W[k] * sc;
            int j = sid[k];
            Ru[j * ROWS + r] = w;
            Tu[r * ROWS + j] = w;
        }
        if (r == 0) Ru[16] = mx;
    }
    __syncthreads();

    // in-LDS renormalized tree 16 -> 8 -> 4 -> 2 -> 1 (r13-proven)
    int lane = threadIdx.x & 63;
    int wid = threadIdx.x >> 6;
#pragma unroll
    for (int q = 0; q < 2; ++q) {
        int p = 2 * wid + q;
        combineUnits(lds, 2 * p, 2 * p + 1, 2 * p, lane);
    }
    __syncthreads();
    if (wid < 4) combineUnits(lds, 4 * wid, 4 * wid + 2, 4 * wid, lane);
    __syncthreads();
    if (wid < 2) combineUnits(lds, 8 * wid, 8 * wid + 4, 8 * wid, lane);
    __syncthreads();
    if (wid == 0) combineUnits(lds, 0, 8, 0, lane);
    __syncthreads();

    // emit: one matrix per block in [j][r] layout + its log2-scale
    wsW[(long)blockIdx.x * 256 + threadIdx.x] =
        lds[(threadIdx.x >> 4) * ROWS + (threadIdx.x & 15)];
    if (threadIdx.x == 0) wsM[blockIdx.x] = lds[16];

    // ---- last-of-b arrival: inline phase23 for this b ----
    float* flagp = lds + 15 * UNIT + 16;   // unit 15 pad hole (unused from here on)
    __threadfence();                        // release wsW/wsM (each thread fences its own)
    __syncthreads();
    if (threadIdx.x == 0) {
        unsigned ref = refW[0];
        unsigned old = atomicAdd(&cntB[b], 1u);
        *flagp = (old - ref == 7u) ? 1.0f : 0.0f;
    }
    __syncthreads();
    if (*flagp != 0.0f) {
        __threadfence();                    // acquire the other 7 blocks' stores
        float* stage = lds;                 // units 0..7
        float* scr   = lds + 8 * UNIT;      // units 8..13
        float* resB  = lds + 14 * UNIT;     // unit 14 (R half)
        // stage 8 matrices in dual layout (r13 staging verbatim)
        const float4* src = (const float4*)(wsW + (long)b * NCP * 256);
#pragma unroll
        for (int q = 0; q < 2; ++q) {
            int f = threadIdx.x + q * 256;
            float4 v = src[f];
            int m = f >> 6, idx = f & 63, j = idx >> 2, kq = idx & 3;
            *(float4*)(stage + m * UNIT + j * ROWS + kq * 4) = v;
            float* Tb = stage + m * UNIT + SLOT;
            Tb[(4 * kq + 0) * ROWS + j] = v.x;
            Tb[(4 * kq + 1) * ROWS + j] = v.y;
            Tb[(4 * kq + 2) * ROWS + j] = v.z;
            Tb[(4 * kq + 3) * ROWS + j] = v.w;
        }
        __syncthreads();
        if (wid < 4)
            mat16_mul(scr + wid * UNIT, scr + wid * UNIT + SLOT,
                      stage + (2 * wid + 1) * UNIT, stage + (2 * wid) * UNIT + SLOT, lane);
        __syncthreads();
        if (wid < 2)
            mat16_mul(scr + (4 + wid) * UNIT, scr + (4 + wid) * UNIT + SLOT,
                      scr + (2 * wid + 1) * UNIT, scr + (2 * wid) * UNIT + SLOT, lane);
        __syncthreads();
        if (wid == 0)
            mat16_mul(resB, nullptr, scr + 5 * UNIT, scr + 4 * UNIT + SLOT, lane);
        __syncthreads();
        // epilogue (r13 verbatim, result -> resOut[b])
        if (threadIdx.x < 16) {
            int jj = threadIdx.x;
            float ls2 = log_sigma[jj];
            float mk2 = mu[jj];
            float iv2 = fexp2(-2.0f * LOG2E * ls2);
            float A2e = -0.5f * LOG2E * iv2;
            float B2e = LOG2E * mk2 * iv2;
            float C2e = LOG2E * (-0.5f * mk2 * mk2 * iv2 - ls2 - HLOG2PI);
            float x = obvs[(long)b * NS];                   // t = 0
            float e = fexp2(LOG2E * prior_logits[jj]);
            float Z = gsum16(e);
            float p0 = fexp2(fmaf(x, fmaf(x, A2e, B2e), C2e)) * e;
            const float* Mrow = resB + jj * ROWS;
            float mr[16];
            *(float4*)&mr[0]  = ((const float4*)Mrow)[0];
            *(float4*)&mr[4]  = ((const float4*)Mrow)[1];
            *(float4*)&mr[8]  = ((const float4*)Mrow)[2];
            *(float4*)&mr[12] = ((const float4*)Mrow)[3];
            float q = 0.0f;
#pragma unroll
            for (int rr = 0; rr < 16; ++rr) q = fmaf(mr[rr], __shfl(p0, rr, 16), q);
            float Tq = gsum16(q);
            float pm = (jj < NCP) ? wsM[b * NCP + jj] : 0.0f;
            float msum = gsum16(pm);
            if (jj == 0) resOut[b] = (flog2(Tq) - flog2(Z) + msum) * LN2;
        }
    }

    // ---- globally-last arrival: sum resOut -> out[0] ----
    __threadfence();                        // release resOut (epilogue blocks)
    __syncthreads();
    if (threadIdx.x == 0) {
        unsigned ref = refW[0];
        unsigned old = atomicAdd(cntG, 1u);
        *flagp = (old - ref == 1023u) ? 1.0f : 0.0f;
    }
    __syncthreads();
    if (*flagp != 0.0f) {
        __threadfence();                    // acquire all resOut
        float v = (threadIdx.x < NB) ? resOut[threadIdx.x] : 0.0f;
        v += __shfl_xor(v, 32); v += __shfl_xor(v, 16); v += __shfl_xor(v, 8);
        v += __shfl_xor(v, 4);  v += __shfl_xor(v, 2);  v += __shfl_xor(v, 1);
        if ((threadIdx.x & 63) == 0) lds[15 * UNIT + (threadIdx.x >> 6)] = v;
        __syncthreads();
        if (threadIdx.x == 0)
            out[0] = (lds[15 * UNIT] + lds[15 * UNIT + 1]) +
                     (lds[15 * UNIT + 2] + lds[15 * UNIT + 3]);
    }
}

extern "C" void kernel_launch(void* const* d_in, const int* in_sizes, int n_in,
                              void* d_out, int out_size, void* d_ws, size_t ws_size,
                              hipStream_t stream) {
    const float* obvs = (const float*)d_in[0];
    const float* mu = (const float*)d_in[1];
    const float* log_sigma = (const float*)d_in[2];
    const float* prior_logits = (const float*)d_in[3];
    float* out = (float*)d_out;

    float* wsW = (float*)d_ws;                          // 1024*256 floats = 1.05 MB
    float* wsM = wsW + (size_t)NB * NCP * 256;          // 1024 floats
    float* resOut = wsM + (size_t)NB * NCP;             // 128 floats
    unsigned* cntB = (unsigned*)(resOut + NB);          // 128 u32 (poisoned uniform)
    unsigned* cntG = cntB + NB;                         // 1 u32
    unsigned* refW = cntG + 1;                          // 1 u32, NEVER written

    hmm_fused<<<dim3(NB * NC * 16 / 256), dim3(256), 0, stream>>>(
        obvs, mu, log_sigma, prior_logits, wsW, wsM, resOut, cntB, cntG, refW, out);
}

// Round 15
// 94.278 us; speedup vs baseline: 2.5734x; 2.5734x over previous
//
#include <hip/hip_runtime.h>

#define NB 128
#define NS 8192
#define NC 128                // chunks per sequence (64-step chunks)
#define NCP 8                 // combined matrices per sequence (one per block)
#define NL (NS / NC)          // 64 steps per chunk
#define M4 (NL / 4)           // 16 float4 groups

#define LOG2E 1.4426950408889634f
#define HLOG2PI 0.918938533204672742f
#define LN2 0.69314718055994531f

// LDS matrix layout (r6/8/9/11/12/13-proven)
#define ROWS 20          // padded leading dim
#define UNIT 640         // dual unit: R[16x20] + T[16x20]
#define SLOT 320

typedef float v2f __attribute__((ext_vector_type(2)));

__device__ __forceinline__ float fexp2(float x) { return __builtin_amdgcn_exp2f(x); }
__device__ __forceinline__ float flog2(float x) { return __builtin_amdgcn_logf(x); }

__device__ __forceinline__ float gsum16(float v) {
    v += __shfl_xor(v, 1, 16);
    v += __shfl_xor(v, 2, 16);
    v += __shfl_xor(v, 4, 16);
    v += __shfl_xor(v, 8, 16);
    return v;
}
__device__ __forceinline__ float gmax16(float v) {
    v = fmaxf(v, __shfl_xor(v, 1, 16));
    v = fmaxf(v, __shfl_xor(v, 2, 16));
    v = fmaxf(v, __shfl_xor(v, 4, 16));
    v = fmaxf(v, __shfl_xor(v, 8, 16));
    return v;
}

template <int K>
__device__ __forceinline__ int rotk(int x) {
    return __builtin_amdgcn_mov_dpp(x, 0x120 + K, 0xF, 0xF, true);
}

// One HMM step, rotated-W layout, PACKED fp32 (r9-proven v_pk_* form).
// Takes current colsum T, returns new colsum. Renorm lives outside.
__device__ __forceinline__ float step2(v2f (&Wv)[8], float T, float xx,
                                       float A2, float B2, float C2) {
    const float amb = 0.9f - 0.1f / 15.0f;
    const float bco = 0.1f / 15.0f;
    float myl = fexp2(fmaf(xx, fmaf(xx, A2, B2), C2));   // ONE exp per lane
    int mi = __float_as_int(myl);
    float bT = bco * T;
    v2f bT2 = {bT, bT};
    v2f amb2 = {amb, amb};
    v2f L0 = {myl,                          __int_as_float(rotk<1>(mi))};
    v2f L1 = {__int_as_float(rotk<2>(mi)),  __int_as_float(rotk<3>(mi))};
    v2f L2 = {__int_as_float(rotk<4>(mi)),  __int_as_float(rotk<5>(mi))};
    v2f L3 = {__int_as_float(rotk<6>(mi)),  __int_as_float(rotk<7>(mi))};
    v2f L4 = {__int_as_float(rotk<8>(mi)),  __int_as_float(rotk<9>(mi))};
    v2f L5 = {__int_as_float(rotk<10>(mi)), __int_as_float(rotk<11>(mi))};
    v2f L6 = {__int_as_float(rotk<12>(mi)), __int_as_float(rotk<13>(mi))};
    v2f L7 = {__int_as_float(rotk<14>(mi)), __int_as_float(rotk<15>(mi))};
    Wv[0] = __builtin_elementwise_fma(amb2, Wv[0], bT2) * L0;
    Wv[1] = __builtin_elementwise_fma(amb2, Wv[1], bT2) * L1;
    Wv[2] = __builtin_elementwise_fma(amb2, Wv[2], bT2) * L2;
    Wv[3] = __builtin_elementwise_fma(amb2, Wv[3], bT2) * L3;
    Wv[4] = __builtin_elementwise_fma(amb2, Wv[4], bT2) * L4;
    Wv[5] = __builtin_elementwise_fma(amb2, Wv[5], bT2) * L5;
    Wv[6] = __builtin_elementwise_fma(amb2, Wv[6], bT2) * L6;
    Wv[7] = __builtin_elementwise_fma(amb2, Wv[7], bT2) * L7;
    v2f s = ((Wv[0] + Wv[1]) + (Wv[2] + Wv[3])) + ((Wv[4] + Wv[5]) + (Wv[6] + Wv[7]));
    return s.x + s.y;
}

// Renormalized product of two LDS dual units (r12/13-proven).
__device__ __forceinline__ void combineUnits(float* lds, int ua, int ub, int ud, int lane) {
    const float* MbR = lds + ub * UNIT;
    const float* MaT = lds + ua * UNIT + SLOT;
    float mxa = lds[ua * UNIT + 16];
    float mxb = lds[ub * UNIT + 16];
    int a = lane >> 3, cc = lane & 7;
    float b0[16], b1[16], a0[16], a1[16];
    const float4* pb0 = (const float4*)(MbR + (2 * a) * ROWS);
    const float4* pb1 = (const float4*)(MbR + (2 * a + 1) * ROWS);
    const float4* pa0 = (const float4*)(MaT + (2 * cc) * ROWS);
    const float4* pa1 = (const float4*)(MaT + (2 * cc + 1) * ROWS);
#pragma unroll
    for (int q = 0; q < 4; ++q) {
        *(float4*)&b0[4 * q] = pb0[q];
        *(float4*)&b1[4 * q] = pb1[q];
        *(float4*)&a0[4 * q] = pa0[q];
        *(float4*)&a1[4 * q] = pa1[q];
    }
    float c00 = 0.f, c01 = 0.f, c10 = 0.f, c11 = 0.f;
#pragma unroll
    for (int k = 0; k < 16; ++k) {
        c00 = fmaf(b0[k], a0[k], c00);
        c01 = fmaf(b0[k], a1[k], c01);
        c10 = fmaf(b1[k], a0[k], c10);
        c11 = fmaf(b1[k], a1[k], c11);
    }
    float cs0 = c00 + c10;
    float cs1 = c01 + c11;
    cs0 += __shfl_xor(cs0, 8);  cs1 += __shfl_xor(cs1, 8);
    cs0 += __shfl_xor(cs0, 16); cs1 += __shfl_xor(cs1, 16);
    cs0 += __shfl_xor(cs0, 32); cs1 += __shfl_xor(cs1, 32);
    float mxc = fmaxf(cs0, cs1);
    mxc = fmaxf(mxc, __shfl_xor(mxc, 1));
    mxc = fmaxf(mxc, __shfl_xor(mxc, 2));
    mxc = fmaxf(mxc, __shfl_xor(mxc, 4));
    float is = 1.0f / mxc;
    c00 *= is; c01 *= is; c10 *= is; c11 *= is;
    float* dR = lds + ud * UNIT;
    float* dT = lds + ud * UNIT + SLOT;
    *(float2*)(dR + (2 * a) * ROWS + 2 * cc)     = make_float2(c00, c01);
    *(float2*)(dR + (2 * a + 1) * ROWS + 2 * cc) = make_float2(c10, c11);
    *(float2*)(dT + (2 * cc) * ROWS + 2 * a)     = make_float2(c00, c10);
    *(float2*)(dT + (2 * cc + 1) * ROWS + 2 * a) = make_float2(c01, c11);
    if (lane == 0) lds[ud * UNIT + 16] = mxa + mxb + flog2(mxc);
}

// Phase 1 (r13 skeleton, r9 packed step): thread (b, chunk c, column r) evolves
// basis e_r through a 64-step chunk, block tree-combines its 16 chunks 16->1
// with per-level renormalization (INVARIANT: every stored/combined matrix is
// max-colsum-normalized). NO single-kernel fusion: device-scope fences flush
// per-XCD L2 on gfx950 — r14's fused version ran 5x slower (223 µs, VALU 12%).
__global__ __launch_bounds__(256, 4) void hmm_phase1(const float* __restrict__ obvs,
                                                     const float* __restrict__ mu,
                                                     const float* __restrict__ log_sigma,
                                                     float* __restrict__ wsW,
                                                     float* __restrict__ wsM,
                                                     float* __restrict__ out) {
    __shared__ float lds[16 * UNIT];       // 16 dual units, 40,960 B
    int tid = blockIdx.x * 256 + threadIdx.x;
    if (tid == 0) out[0] = 0.0f;           // phase23 atomicAdds after this dispatch
    int r = threadIdx.x & 15;
    int u = threadIdx.x >> 4;              // local chunk 0..15
    int g = tid >> 4;                      // g = b*NC + c
    int b = g >> 7;
    int c = g & (NC - 1);

    float ls = log_sigma[r];
    float mk = mu[r];
    float iv = fexp2(-2.0f * LOG2E * ls);
    float A2 = -0.5f * LOG2E * iv;
    float B2 = LOG2E * mk * iv;
    float C2 = LOG2E * (-0.5f * mk * mk * iv - ls - HLOG2PI);

    v2f Wv[8];
#pragma unroll
    for (int i = 0; i < 8; ++i) Wv[i] = (v2f){0.0f, 0.0f};
    Wv[0].x = 1.0f;                        // identity in rotated layout
    int ilog = 0;
    float T = 1.0f;

    const float4* ob4 = (const float4*)(obvs + (long)b * NS) + c * M4;
    float4 xv = ob4[0];
    float4 xn = ob4[1];
    // peeled m=0 group: chunk 0 skips t=0 (handled as init vector in phase23)
    if (c) T = step2(Wv, T, xv.x, A2, B2, C2);
    T = step2(Wv, T, xv.y, A2, B2, C2);
    T = step2(Wv, T, xv.z, A2, B2, C2);
    T = step2(Wv, T, xv.w, A2, B2, C2);
    {
        int te = (__float_as_int(T) >> 23) & 255;
        int ok = (te != 0);
        float s = ok ? __int_as_float((254 - te) << 23) : 1.0f;
        ilog += ok ? (te - 127) : 0;
        v2f s2 = {s, s};
#pragma unroll
        for (int i = 0; i < 8; ++i) Wv[i] *= s2;
        T *= s;
    }
    xv = xn;
    for (int m = 1; m < M4; ++m) {
        xn = ob4[(m + 1) < M4 ? (m + 1) : m];
        T = step2(Wv, T, xv.x, A2, B2, C2);
        T = step2(Wv, T, xv.y, A2, B2, C2);
        T = step2(Wv, T, xv.z, A2, B2, C2);
        T = step2(Wv, T, xv.w, A2, B2, C2);
        // guarded branchless exponent renorm (r8/9/11/12/13-proven)
        int te = (__float_as_int(T) >> 23) & 255;
        int ok = (te != 0);
        float s = ok ? __int_as_float((254 - te) << 23) : 1.0f;
        ilog += ok ? (te - 127) : 0;
        v2f s2 = {s, s};
#pragma unroll
        for (int i = 0; i < 8; ++i) Wv[i] *= s2;
        T *= s;
        xv = xn;
    }

    int sid[16];
    sid[0] = r;
    sid[1]  = rotk<1>(r);   sid[2]  = rotk<2>(r);   sid[3]  = rotk<3>(r);
    sid[4]  = rotk<4>(r);   sid[5]  = rotk<5>(r);   sid[6]  = rotk<6>(r);
    sid[7]  = rotk<7>(r);   sid[8]  = rotk<8>(r);   sid[9]  = rotk<9>(r);
    sid[10] = rotk<10>(r);  sid[11] = rotk<11>(r);  sid[12] = rotk<12>(r);
    sid[13] = rotk<13>(r);  sid[14] = rotk<14>(r);  sid[15] = rotk<15>(r);

    float lg = (float)ilog + flog2(T);     // true column log2-sum (T in [1,2))
    float mx = gmax16(lg);                 // chunk max over 16 columns
    float sc = fexp2((float)ilog - mx);    // scale so chunk max colsum = 1

    // normalized chunk matrix into LDS dual layout (r9's paired store, LDS target)
    float* Ru = lds + u * UNIT;
    float* Tu = lds + u * UNIT + SLOT;
#pragma unroll
    for (int i = 0; i < 8; ++i) {
        float w0 = Wv[i].x * sc;
        float w1 = Wv[i].y * sc;
        int j0 = sid[2 * i], j1 = sid[2 * i + 1];
        Ru[j0 * ROWS + r] = w0;
        Ru[j1 * ROWS + r] = w1;
        Tu[r * ROWS + j0] = w0;
        Tu[r * ROWS + j1] = w1;
    }
    if (r == 0) Ru[16] = mx;
    __syncthreads();

    // in-LDS renormalized tree 16 -> 8 -> 4 -> 2 -> 1 (r13-proven)
    int lane = threadIdx.x & 63;
    int wid = threadIdx.x >> 6;
#pragma unroll
    for (int q = 0; q < 2; ++q) {
        int p = 2 * wid + q;
        combineUnits(lds, 2 * p, 2 * p + 1, 2 * p, lane);
    }
    __syncthreads();
    if (wid < 4) combineUnits(lds, 4 * wid, 4 * wid + 2, 4 * wid, lane);
    __syncthreads();
    if (wid < 2) combineUnits(lds, 8 * wid, 8 * wid + 4, 8 * wid, lane);
    __syncthreads();
    if (wid == 0) combineUnits(lds, 0, 8, 0, lane);
    __syncthreads();

    // emit: one matrix per block in [j][r] layout + its log2-scale
    wsW[(long)blockIdx.x * 256 + threadIdx.x] =
        lds[(threadIdx.x >> 4) * ROWS + (threadIdx.x & 15)];
    if (threadIdx.x == 0) wsM[blockIdx.x] = lds[16];
}

// P = Mb * Ma, one product per wave, unnormalized (r13 epilogue tree; 3 levels safe).
__device__ __forceinline__ void mat16_mul(float* dR, float* dT,
                                          const float* MbR, const float* MaT,
                                          int lane) {
    int a = lane >> 3;
    int cc = lane & 7;
    float b0[16], b1[16], a0[16], a1[16];
    const float4* pb0 = (const float4*)(MbR + (2 * a) * ROWS);
    const float4* pb1 = (const float4*)(MbR + (2 * a + 1) * ROWS);
    const float4* pa0 = (const float4*)(MaT + (2 * cc) * ROWS);
    const float4* pa1 = (const float4*)(MaT + (2 * cc + 1) * ROWS);
#pragma unroll
    for (int q = 0; q < 4; ++q) {
        *(float4*)&b0[4 * q] = pb0[q];
        *(float4*)&b1[4 * q] = pb1[q];
        *(float4*)&a0[4 * q] = pa0[q];
        *(float4*)&a1[4 * q] = pa1[q];
    }
    float c00 = 0.f, c01 = 0.f, c10 = 0.f, c11 = 0.f;
#pragma unroll
    for (int k = 0; k < 16; ++k) {
        c00 = fmaf(b0[k], a0[k], c00);
        c01 = fmaf(b0[k], a1[k], c01);
        c10 = fmaf(b1[k], a0[k], c10);
        c11 = fmaf(b1[k], a1[k], c11);
    }
    *(float2*)(dR + (2 * a) * ROWS + 2 * cc)     = make_float2(c00, c01);
    *(float2*)(dR + (2 * a + 1) * ROWS + 2 * cc) = make_float2(c10, c11);
    if (dT) {
        *(float2*)(dT + (2 * cc) * ROWS + 2 * a)     = make_float2(c00, c10);
        *(float2*)(dT + (2 * cc + 1) * ROWS + 2 * a) = make_float2(c01, c11);
    }
}

// Phase 2+3: VERBATIM r13-passed kernel (8 input matrices per b).
__global__ __launch_bounds__(256, 2) void hmm_phase23(const float* __restrict__ obvs,
                                                      const float* __restrict__ mu,
                                                      const float* __restrict__ log_sigma,
                                                      const float* __restrict__ prior_logits,
                                                      const float* __restrict__ wsW,
                                                      const float* __restrict__ wsM,
                                                      float* __restrict__ out) {
    __shared__ float smem[10560];   // stage(8x640) + scr(8x640) + resB(320)
    float* stage = smem;
    float* scr   = smem + 5120;
    float* resB  = smem + 10240;

    int bb = blockIdx.x;
    int tid = threadIdx.x;
    int wid = tid >> 6;
    int lane = tid & 63;

    // stage 8 matrices in dual layout
    const float4* src = (const float4*)(wsW + (long)bb * NCP * 256);
#pragma unroll
    for (int q = 0; q < 2; ++q) {
        int f = tid + q * 256;
        float4 v = src[f];
        int m = f >> 6, idx = f & 63, j = idx >> 2, kq = idx & 3;
        *(float4*)(stage + m * UNIT + j * ROWS + kq * 4) = v;
        float* Tb = stage + m * UNIT + SLOT;
        Tb[(4 * kq + 0) * ROWS + j] = v.x;
        Tb[(4 * kq + 1) * ROWS + j] = v.y;
        Tb[(4 * kq + 2) * ROWS + j] = v.z;
        Tb[(4 * kq + 3) * ROWS + j] = v.w;
    }
    __syncthreads();
    // tree 8 -> 4 -> 2 -> 1  (later * earlier)
    if (wid < 4)
        mat16_mul(scr + wid * UNIT, scr + wid * UNIT + SLOT,
                  stage + (2 * wid + 1) * UNIT, stage + (2 * wid) * UNIT + SLOT, lane);
    __syncthreads();
    if (wid < 2)
        mat16_mul(scr + (4 + wid) * UNIT, scr + (4 + wid) * UNIT + SLOT,
                  scr + (2 * wid + 1) * UNIT, scr + (2 * wid) * UNIT + SLOT, lane);
    __syncthreads();
    if (wid == 0)
        mat16_mul(resB, nullptr, scr + 5 * UNIT, scr + 4 * UNIT + SLOT, lane);
    __syncthreads();
    // final combined matrix rows at resB[j*ROWS + k]

    if (tid < 16) {
        int jj = tid;
        float ls = log_sigma[jj];
        float mk = mu[jj];
        float iv = fexp2(-2.0f * LOG2E * ls);
        float A2 = -0.5f * LOG2E * iv;
        float B2 = LOG2E * mk * iv;
        float C2 = LOG2E * (-0.5f * mk * mk * iv - ls - HLOG2PI);
        float x = obvs[(long)bb * NS];                   // t = 0
        float e = fexp2(LOG2E * prior_logits[jj]);
        float Z = gsum16(e);
        float p0 = fexp2(fmaf(x, fmaf(x, A2, B2), C2)) * e;
        const float* Mrow = resB + jj * ROWS;
        float mr[16];
        *(float4*)&mr[0]  = ((const float4*)Mrow)[0];
        *(float4*)&mr[4]  = ((const float4*)Mrow)[1];
        *(float4*)&mr[8]  = ((const float4*)Mrow)[2];
        *(float4*)&mr[12] = ((const float4*)Mrow)[3];
        float q = 0.0f;
#pragma unroll
        for (int rr = 0; rr < 16; ++rr) q = fmaf(mr[rr], __shfl(p0, rr, 16), q);
        float Tq = gsum16(q);
        float pm = (jj < NCP) ? wsM[bb * NCP + jj] : 0.0f;
        float msum = gsum16(pm);
        if (jj == 0) {
            float res = (flog2(Tq) - flog2(Z) + msum) * LN2;
            atomicAdd(out, res);
        }
    }
}

extern "C" void kernel_launch(void* const* d_in, const int* in_sizes, int n_in,
                              void* d_out, int out_size, void* d_ws, size_t ws_size,
                              hipStream_t stream) {
    const float* obvs = (const float*)d_in[0];
    const float* mu = (const float*)d_in[1];
    const float* log_sigma = (const float*)d_in[2];
    const float* prior_logits = (const float*)d_in[3];
    float* out = (float*)d_out;

    float* wsW = (float*)d_ws;                          // NB*NCP*256 floats = 1.05 MB
    float* wsM = wsW + (size_t)NB * NCP * 256;          // NB*NCP floats

    hmm_phase1<<<dim3(NB * NC * 16 / 256), dim3(256), 0, stream>>>(obvs, mu, log_sigma,
                                                                   wsW, wsM, out);
    hmm_phase23<<<dim3(NB), dim3(256), 0, stream>>>(obvs, mu, log_sigma, prior_logits,
                                                    wsW, wsM, out);
}